// Round 6
// baseline (131.155 us; speedup 1.0000x reference)
//
#include <hip/hip_runtime.h>

#define N_ATOMS 100000
#define KNBR    16
#define EPSF    1e-12f
#define BLOCK   256
#define NBLK    ((N_ATOMS * KNBR) / BLOCK)   // 6250, exact
#define FRCP(x) __builtin_amdgcn_rcpf(x)

// Pack coords+element into one float4 per atom; reset the block-completion counter.
__global__ __launch_bounds__(256) void sw_pack(const float* __restrict__ coords,
                                               const int* __restrict__ elems,
                                               float4* __restrict__ pk,
                                               unsigned* __restrict__ counter) {
    const int i = blockIdx.x * 256 + threadIdx.x;
    if (i == 0) *counter = 0u;
    if (i < N_ATOMS) {
        pk[i] = make_float4(coords[3 * i + 0], coords[3 * i + 1], coords[3 * i + 2],
                            __int_as_float(elems[i]));
    }
}

// One thread per (atom, neighbor) pair. 16-lane groups own one atom; 3-body
// eligibility compacted cross-lane via ballot + prefix-popcount into LDS.
// Per-block partials -> contention-free stores; last block reduces them (no 3rd kernel).
__global__ __launch_bounds__(BLOCK) void sw_pairs(
    const float4* __restrict__ pk, const int* __restrict__ nbr,
    const float* __restrict__ Ap, const float* __restrict__ Bp,
    const float* __restrict__ pp, const float* __restrict__ qp,
    const float* __restrict__ sigp, const float* __restrict__ gamp,
    const float* __restrict__ cutp, const float* __restrict__ lamp,
    const float* __restrict__ cb0p, const float* __restrict__ cjkp,
    float* __restrict__ partial, unsigned* __restrict__ counter,
    float* __restrict__ out)
{
    __shared__ float4 comp[BLOCK / 16][16];   // per-atom compacted eligible neighbors
    __shared__ float wsum[BLOCK / 64];
    __shared__ int amLast;

    const int t    = blockIdx.x * BLOCK + threadIdx.x;  // pair id (grid sized exactly)
    const int i    = t >> 4;                            // atom id
    const int gl   = threadIdx.x & 15;                  // neighbor slot within atom
    const int lane = threadIdx.x & 63;
    const int grp  = threadIdx.x >> 4;                  // local atom index (0..15)

    // uniform params -> scalar loads
    const float c0 = cutp[0], c1 = cutp[1], c2 = cutp[2];
    const float s0 = sigp[0], s1 = sigp[1], s2 = sigp[2];
    const float A0 = Ap[0],  A1 = Ap[1],  A2 = Ap[2];
    const float B0 = Bp[0],  B1 = Bp[1],  B2 = Bp[2];
    const float P0 = pp[0],  P1 = pp[1],  P2 = pp[2];
    const float Q0 = qp[0],  Q1 = qp[1],  Q2 = qp[2];
    const float g1 = gamp[1];
    // this instance: p==5, q==0 -> sr^p = sr^5 (3 muls), sr^q = 1 (uniform branch)
    const bool fastpq = (P0 == 5.f && P1 == 5.f && P2 == 5.f &&
                         Q0 == 0.f && Q1 == 0.f && Q2 == 0.f);

    float acc = 0.0f;
    bool  elig = false;
    float dx = 0.f, dy = 0.f, dz = 0.f, rij = 1.f;
    int   ei = 0;

    {
        const int    nj = nbr[t];      // fully coalesced 4B/lane
        const float4 pj = pk[nj];      // one random 16B gather (L2-resident table)
        const float4 pi = pk[i];       // same addr across 16 lanes -> broadcast
        ei = __float_as_int(pi.w);
        const int ej = __float_as_int(pj.w);
        dx = pj.x - pi.x; dy = pj.y - pi.y; dz = pj.z - pi.z;
        const float r2  = fmaxf(dx * dx + dy * dy + dz * dz, EPSF);
        const int   ij  = ei + ej;
        const float cut = (ij == 0) ? c0 : ((ij == 1) ? c1 : c2);
        if (r2 < cut * cut) {
            rij = sqrtf(r2);
            const float sg  = (ij == 0) ? s0 : ((ij == 1) ? s1 : s2);
            const float Aij = (ij == 0) ? A0 : ((ij == 1) ? A1 : A2);
            const float Bij = (ij == 0) ? B0 : ((ij == 1) ? B1 : B2);
            const float sr  = sg * FRCP(rij);
            float srp, srq;
            if (fastpq) {
                const float sr2 = sr * sr;
                srp = sr2 * sr2 * sr;  srq = 1.0f;
            } else {
                const float Pij = (ij == 0) ? P0 : ((ij == 1) ? P1 : P2);
                const float Qij = (ij == 0) ? Q0 : ((ij == 1) ? Q1 : Q2);
                srp = __powf(sr, Pij); srq = __powf(sr, Qij);
            }
            acc  = 0.5f * Aij * (Bij * srp - srq) * __expf(sg * FRCP(rij - cut));
            elig = (ej != ei);        // 3-body eligible (=> ij==1, cut==c1)
        }
    }

    // cross-lane compaction within each 16-lane group
    const unsigned long long bal = __ballot(elig);
    const unsigned gmask = (unsigned)((bal >> (lane & 48)) & 0xFFFFull);
    const int slot = __popc(gmask & ((1u << gl) - 1u));
    if (elig) comp[grp][slot] = make_float4(dx, dy, dz, rij);
    __syncthreads();

    // triangular 3-body: lane b pairs with earlier compacted slots a < slot
    if (elig && slot > 0) {
        const float lam_i = lamp[ei];
        const float cb0_i = cb0p[ei];
        const float cjk   = cjkp[ei];
        const float cjk2  = cjk * cjk;
        const float rb = rij;
        const float eb = g1 * FRCP(rb - c1);
        for (int a = 0; a < slot; ++a) {
            const float4 pa = comp[grp][a];
            const float ddx = pa.x - dx, ddy = pa.y - dy, ddz = pa.z - dz;
            const float rjk2 = fmaxf(ddx * ddx + ddy * ddy + ddz * ddz, EPSF);
            if (rjk2 < cjk2) {
                const float ra   = pa.w;
                const float ea   = g1 * FRCP(ra - c1);
                const float cosv = (ra * ra + rb * rb - rjk2) * 0.5f * FRCP(ra * rb);
                const float dcs  = cosv - cb0_i;
                acc += lam_i * __expf(ea + eb) * dcs * dcs;
            }
        }
    }

    // wave reduce (64 lanes) -> block reduce -> contention-free partial store
    for (int o = 32; o > 0; o >>= 1) acc += __shfl_down(acc, o);
    if (lane == 0) wsum[threadIdx.x >> 6] = acc;
    __syncthreads();
    if (threadIdx.x == 0) {
        float s = 0.0f;
        for (int w = 0; w < BLOCK / 64; ++w) s += wsum[w];
        __hip_atomic_store(&partial[blockIdx.x], s, __ATOMIC_RELAXED,
                           __HIP_MEMORY_SCOPE_AGENT);
        const unsigned prev = __hip_atomic_fetch_add(counter, 1u, __ATOMIC_ACQ_REL,
                                                     __HIP_MEMORY_SCOPE_AGENT);
        amLast = (prev == NBLK - 1);
    }
    __syncthreads();

    // last finishing block reduces all partials and writes the scalar output
    if (amLast) {
        float s2 = 0.0f;
        for (int k = threadIdx.x; k < NBLK; k += BLOCK)
            s2 += __hip_atomic_load(&partial[k], __ATOMIC_RELAXED,
                                    __HIP_MEMORY_SCOPE_AGENT);
        for (int o = 32; o > 0; o >>= 1) s2 += __shfl_down(s2, o);
        if (lane == 0) wsum[threadIdx.x >> 6] = s2;
        __syncthreads();
        if (threadIdx.x == 0) {
            float r = 0.0f;
            for (int w = 0; w < BLOCK / 64; ++w) r += wsum[w];
            out[0] = r;
        }
    }
}

extern "C" void kernel_launch(void* const* d_in, const int* in_sizes, int n_in,
                              void* d_out, int out_size, void* d_ws, size_t ws_size,
                              hipStream_t stream) {
    const float* coords = (const float*)d_in[0];
    const float* A      = (const float*)d_in[1];
    const float* B      = (const float*)d_in[2];
    const float* p      = (const float*)d_in[3];
    const float* q      = (const float*)d_in[4];
    const float* sigma  = (const float*)d_in[5];
    const float* gamma  = (const float*)d_in[6];
    const float* cutoff = (const float*)d_in[7];
    const float* lam    = (const float*)d_in[8];
    const float* cb0    = (const float*)d_in[9];
    const float* cjk    = (const float*)d_in[10];
    const int*   elems  = (const int*)d_in[11];
    const int*   nbr    = (const int*)d_in[12];
    float* out = (float*)d_out;

    float4*   pk      = (float4*)d_ws;                              // 1.6 MB
    float*    partial = (float*)((char*)d_ws + N_ATOMS * 16);       // 25 KB
    unsigned* counter = (unsigned*)((char*)d_ws + N_ATOMS * 16 + NBLK * 4);

    sw_pack<<<(N_ATOMS + 255) / 256, 256, 0, stream>>>(coords, elems, pk, counter);
    sw_pairs<<<NBLK, BLOCK, 0, stream>>>(
        pk, nbr, A, B, p, q, sigma, gamma, cutoff, lam, cb0, cjk,
        partial, counter, out);
}

// Round 7
// 79.757 us; speedup vs baseline: 1.6444x; 1.6444x over previous
//
#include <hip/hip_runtime.h>

#define N_ATOMS 100000
#define KNBR    16
#define TOTAL   (N_ATOMS * KNBR)            // 1,600,000 pairs
#define EPSF    1e-12f
#define BLOCK   256
#define PPT     2                            // pairs per thread
#define NBLK    (TOTAL / (BLOCK * PPT))      // 3125, exact
#define FRCP(x) __builtin_amdgcn_rcpf(x)

// Pack coords+element into one float4 per atom (gather = 1 dwordx4 instead of 4).
__global__ __launch_bounds__(256) void sw_pack(const float* __restrict__ coords,
                                               const int* __restrict__ elems,
                                               float4* __restrict__ pk) {
    const int i = blockIdx.x * 256 + threadIdx.x;
    if (i < N_ATOMS) {
        pk[i] = make_float4(coords[3 * i + 0], coords[3 * i + 1], coords[3 * i + 2],
                            __int_as_float(elems[i]));
    }
}

// One thread per TWO (atom, neighbor) pairs (independent gather chains -> ILP).
// 16-lane groups own one atom per phase; 3-body eligibility compacted cross-lane
// via ballot + prefix-popcount into a group-private LDS region (wave-local: no
// block barrier needed). Per-block partial -> contention-free store.
__global__ __launch_bounds__(BLOCK) void sw_pairs(
    const float4* __restrict__ pk, const int* __restrict__ nbr,
    const float* __restrict__ Ap, const float* __restrict__ Bp,
    const float* __restrict__ pp, const float* __restrict__ qp,
    const float* __restrict__ sigp, const float* __restrict__ gamp,
    const float* __restrict__ cutp, const float* __restrict__ lamp,
    const float* __restrict__ cb0p, const float* __restrict__ cjkp,
    float* __restrict__ partial)
{
    __shared__ float4 comp[BLOCK / 16][16];   // group-private compacted neighbors
    __shared__ float wsum[BLOCK / 64];

    const int tid  = threadIdx.x;
    const int gl   = tid & 15;
    const int lane = tid & 63;
    const int grp  = tid >> 4;

    const int tA = blockIdx.x * BLOCK + tid;  // first pair id
    const int tB = tA + TOTAL / 2;            // second pair id (independent atom)

    // uniform params -> scalar loads
    const float c0 = cutp[0], c1 = cutp[1], c2 = cutp[2];
    const float s0 = sigp[0], s1 = sigp[1], s2 = sigp[2];
    const float A0 = Ap[0],  A1 = Ap[1],  A2 = Ap[2];
    const float B0 = Bp[0],  B1 = Bp[1],  B2 = Bp[2];
    const float P0 = pp[0],  P1 = pp[1],  P2 = pp[2];
    const float Q0 = qp[0],  Q1 = qp[1],  Q2 = qp[2];
    const float g1 = gamp[1];
    const float lam0 = lamp[0], lam1 = lamp[1];
    const float cbA0 = cb0p[0], cbA1 = cb0p[1];
    const float cj0 = cjkp[0], cj1 = cjkp[1];
    // this instance: p==5, q==0 -> sr^p = sr^5 (3 muls), sr^q = 1 (uniform branch)
    const bool fastpq = (P0 == 5.f && P1 == 5.f && P2 == 5.f &&
                         Q0 == 0.f && Q1 == 0.f && Q2 == 0.f);

    // issue all global loads up front: two independent gather chains in flight
    const int    njA = nbr[tA];
    const int    njB = nbr[tB];
    const float4 pjA = pk[njA];
    const float4 pjB = pk[njB];
    const float4 piA = pk[tA >> 4];
    const float4 piB = pk[tB >> 4];

    float acc = 0.0f;

    auto do_pair = [&](const float4& pi, const float4& pj) {
        const int ei = __float_as_int(pi.w);
        const int ej = __float_as_int(pj.w);
        const float dx = pj.x - pi.x, dy = pj.y - pi.y, dz = pj.z - pi.z;
        const float r2  = fmaxf(dx * dx + dy * dy + dz * dz, EPSF);
        const int   ij  = ei + ej;
        const float cut = (ij == 0) ? c0 : ((ij == 1) ? c1 : c2);
        bool  elig = false;
        float rij  = 1.0f;
        if (r2 < cut * cut) {
            rij = sqrtf(r2);
            const float sg  = (ij == 0) ? s0 : ((ij == 1) ? s1 : s2);
            const float Aij = (ij == 0) ? A0 : ((ij == 1) ? A1 : A2);
            const float Bij = (ij == 0) ? B0 : ((ij == 1) ? B1 : B2);
            const float sr  = sg * FRCP(rij);
            float srp, srq;
            if (fastpq) {
                const float sr2 = sr * sr;
                srp = sr2 * sr2 * sr;  srq = 1.0f;
            } else {
                const float Pij = (ij == 0) ? P0 : ((ij == 1) ? P1 : P2);
                const float Qij = (ij == 0) ? Q0 : ((ij == 1) ? Q1 : Q2);
                srp = __powf(sr, Pij); srq = __powf(sr, Qij);
            }
            acc += 0.5f * Aij * (Bij * srp - srq) * __expf(sg * FRCP(rij - cut));
            elig = (ej != ei);        // 3-body eligible (=> ij==1, cut==c1)
        }

        // cross-lane compaction within the 16-lane group (wave-local, no barrier)
        const unsigned long long bal = __ballot(elig);
        const unsigned gmask = (unsigned)((bal >> (lane & 48)) & 0xFFFFull);
        const int slot = __popc(gmask & ((1u << gl) - 1u));
        if (elig) comp[grp][slot] = make_float4(dx, dy, dz, rij);
        // wave-in-order DS ops: reads below see this group's writes (lgkmcnt)

        if (elig && slot > 0) {
            const float lam_i = (ei == 0) ? lam0 : lam1;
            const float cb0_i = (ei == 0) ? cbA0 : cbA1;
            const float cjk   = (ei == 0) ? cj0 : cj1;
            const float cjk2  = cjk * cjk;
            const float rb = rij;
            const float eb = g1 * FRCP(rb - c1);
            for (int a = 0; a < slot; ++a) {
                const float4 pa = comp[grp][a];
                const float ddx = pa.x - dx, ddy = pa.y - dy, ddz = pa.z - dz;
                const float rjk2 = fmaxf(ddx * ddx + ddy * ddy + ddz * ddz, EPSF);
                if (rjk2 < cjk2) {
                    const float ra   = pa.w;
                    const float ea   = g1 * FRCP(ra - c1);
                    const float cosv = (ra * ra + rb * rb - rjk2) * 0.5f * FRCP(ra * rb);
                    const float dcs  = cosv - cb0_i;
                    acc += lam_i * __expf(ea + eb) * dcs * dcs;
                }
            }
        }
    };

    do_pair(piA, pjA);   // phase A
    do_pair(piB, pjB);   // phase B (reuses comp[grp]; same-wave in-order DS ops)

    // wave reduce (64 lanes) -> block reduce -> contention-free partial store
    for (int o = 32; o > 0; o >>= 1) acc += __shfl_down(acc, o);
    if (lane == 0) wsum[tid >> 6] = acc;
    __syncthreads();
    if (tid == 0) {
        float s = 0.0f;
        for (int w = 0; w < BLOCK / 64; ++w) s += wsum[w];
        partial[blockIdx.x] = s;
    }
}

// Single-block final reduction over NBLK partials.
__global__ __launch_bounds__(1024) void sw_reduce(const float* __restrict__ partial,
                                                  float* __restrict__ out) {
    __shared__ float wsum[16];
    float s = 0.0f;
    for (int k = threadIdx.x; k < NBLK; k += 1024) s += partial[k];
    for (int o = 32; o > 0; o >>= 1) s += __shfl_down(s, o);
    if ((threadIdx.x & 63) == 0) wsum[threadIdx.x >> 6] = s;
    __syncthreads();
    if (threadIdx.x == 0) {
        float r = 0.0f;
        for (int w = 0; w < 16; ++w) r += wsum[w];
        out[0] = r;
    }
}

extern "C" void kernel_launch(void* const* d_in, const int* in_sizes, int n_in,
                              void* d_out, int out_size, void* d_ws, size_t ws_size,
                              hipStream_t stream) {
    const float* coords = (const float*)d_in[0];
    const float* A      = (const float*)d_in[1];
    const float* B      = (const float*)d_in[2];
    const float* p      = (const float*)d_in[3];
    const float* q      = (const float*)d_in[4];
    const float* sigma  = (const float*)d_in[5];
    const float* gamma  = (const float*)d_in[6];
    const float* cutoff = (const float*)d_in[7];
    const float* lam    = (const float*)d_in[8];
    const float* cb0    = (const float*)d_in[9];
    const float* cjk    = (const float*)d_in[10];
    const int*   elems  = (const int*)d_in[11];
    const int*   nbr    = (const int*)d_in[12];
    float* out = (float*)d_out;

    float4* pk      = (float4*)d_ws;                          // 1.6 MB
    float*  partial = (float*)((char*)d_ws + N_ATOMS * 16);   // 12.5 KB

    sw_pack<<<(N_ATOMS + 255) / 256, 256, 0, stream>>>(coords, elems, pk);
    sw_pairs<<<NBLK, BLOCK, 0, stream>>>(
        pk, nbr, A, B, p, q, sigma, gamma, cutoff, lam, cb0, cjk, partial);
    sw_reduce<<<1, 1024, 0, stream>>>(partial, out);
}

// Round 8
// 21.784 us; speedup vs baseline: 6.0208x; 3.6613x over previous
//
#include <hip/hip_runtime.h>

#define N_ATOMS 100000
#define KNBR    16
#define TOTAL   (N_ATOMS * KNBR)            // 1,600,000 pairs
#define EPSF    1e-12f
#define BLOCK   256
#define PPT     2                            // pairs per thread
#define NBLK    (TOTAL / (BLOCK * PPT))      // 3125, exact
#define FRCP(x) __builtin_amdgcn_rcpf(x)

// Pack coords+element into one float4 per atom (gather = 1 dwordx4 instead of 4).
__global__ __launch_bounds__(256) void sw_pack(const float* __restrict__ coords,
                                               const int* __restrict__ elems,
                                               float4* __restrict__ pk) {
    const int i = blockIdx.x * 256 + threadIdx.x;
    if (i < N_ATOMS) {
        pk[i] = make_float4(coords[3 * i + 0], coords[3 * i + 1], coords[3 * i + 2],
                            __int_as_float(elems[i]));
    }
}

// Straight-line per-pair body as a MACRO — no device lambda (by-ref lambda
// captures forced a scratch frame: round-7 WRITE_SIZE=284MB of spill traffic).
#define DO_PAIR(PI, PJ)                                                         \
    {                                                                           \
        const int   ei = __float_as_int((PI).w);                                \
        const int   ej = __float_as_int((PJ).w);                                \
        const float dx = (PJ).x - (PI).x;                                       \
        const float dy = (PJ).y - (PI).y;                                       \
        const float dz = (PJ).z - (PI).z;                                       \
        const float r2  = fmaxf(dx * dx + dy * dy + dz * dz, EPSF);             \
        const int   ij  = ei + ej;                                              \
        const float cut = (ij == 0) ? c0 : ((ij == 1) ? c1 : c2);               \
        bool  elig = false;                                                     \
        float rij  = 1.0f;                                                      \
        if (r2 < cut * cut) {                                                   \
            rij = sqrtf(r2);                                                    \
            const float sg  = (ij == 0) ? s0 : ((ij == 1) ? s1 : s2);           \
            const float Aij = (ij == 0) ? A0 : ((ij == 1) ? A1 : A2);           \
            const float Bij = (ij == 0) ? B0 : ((ij == 1) ? B1 : B2);           \
            const float sr  = sg * FRCP(rij);                                   \
            float srp, srq;                                                     \
            if (fastpq) {                                                       \
                const float sr2 = sr * sr;                                      \
                srp = sr2 * sr2 * sr;  srq = 1.0f;                              \
            } else {                                                            \
                const float Pij = (ij == 0) ? P0 : ((ij == 1) ? P1 : P2);       \
                const float Qij = (ij == 0) ? Q0 : ((ij == 1) ? Q1 : Q2);       \
                srp = __powf(sr, Pij); srq = __powf(sr, Qij);                   \
            }                                                                   \
            acc += 0.5f * Aij * (Bij * srp - srq) * __expf(sg * FRCP(rij - cut)); \
            elig = (ej != ei);   /* 3-body eligible (=> ij==1, cut==c1) */      \
        }                                                                       \
        const unsigned long long bal = __ballot(elig);                          \
        const unsigned gmask = (unsigned)((bal >> (lane & 48)) & 0xFFFFull);    \
        const int slot = __popc(gmask & ((1u << gl) - 1u));                     \
        if (elig) comp[grp][slot] = make_float4(dx, dy, dz, rij);               \
        /* 16-lane group lives in one wave64: in-order DS ops, no barrier */    \
        if (elig && slot > 0) {                                                 \
            const float lam_i = (ei == 0) ? lam0 : lam1;                        \
            const float cb0_i = (ei == 0) ? cbA0 : cbA1;                        \
            const float cjk   = (ei == 0) ? cj0 : cj1;                          \
            const float cjk2  = cjk * cjk;                                      \
            const float rb = rij;                                               \
            const float eb = g1 * FRCP(rb - c1);                                \
            for (int a = 0; a < slot; ++a) {                                    \
                const float4 pa = comp[grp][a];                                 \
                const float ddx = pa.x - dx, ddy = pa.y - dy, ddz = pa.z - dz;  \
                const float rjk2 = fmaxf(ddx * ddx + ddy * ddy + ddz * ddz, EPSF); \
                if (rjk2 < cjk2) {                                              \
                    const float ra   = pa.w;                                    \
                    const float ea   = g1 * FRCP(ra - c1);                      \
                    const float cosv = (ra * ra + rb * rb - rjk2) * 0.5f * FRCP(ra * rb); \
                    const float dcs  = cosv - cb0_i;                            \
                    acc += lam_i * __expf(ea + eb) * dcs * dcs;                 \
                }                                                               \
            }                                                                   \
        }                                                                       \
    }

// One thread per TWO (atom, neighbor) pairs (independent gather chains -> ILP).
__global__ __launch_bounds__(BLOCK) void sw_pairs(
    const float4* __restrict__ pk, const int* __restrict__ nbr,
    const float* __restrict__ Ap, const float* __restrict__ Bp,
    const float* __restrict__ pp, const float* __restrict__ qp,
    const float* __restrict__ sigp, const float* __restrict__ gamp,
    const float* __restrict__ cutp, const float* __restrict__ lamp,
    const float* __restrict__ cb0p, const float* __restrict__ cjkp,
    float* __restrict__ partial)
{
    __shared__ float4 comp[BLOCK / 16][16];   // group-private compacted neighbors
    __shared__ float wsum[BLOCK / 64];

    const int tid  = threadIdx.x;
    const int gl   = tid & 15;
    const int lane = tid & 63;
    const int grp  = tid >> 4;

    const int tA = blockIdx.x * BLOCK + tid;  // first pair id
    const int tB = tA + TOTAL / 2;            // second pair id (independent atom)

    // uniform params -> scalar loads
    const float c0 = cutp[0], c1 = cutp[1], c2 = cutp[2];
    const float s0 = sigp[0], s1 = sigp[1], s2 = sigp[2];
    const float A0 = Ap[0],  A1 = Ap[1],  A2 = Ap[2];
    const float B0 = Bp[0],  B1 = Bp[1],  B2 = Bp[2];
    const float P0 = pp[0],  P1 = pp[1],  P2 = pp[2];
    const float Q0 = qp[0],  Q1 = qp[1],  Q2 = qp[2];
    const float g1 = gamp[1];
    const float lam0 = lamp[0], lam1 = lamp[1];
    const float cbA0 = cb0p[0], cbA1 = cb0p[1];
    const float cj0 = cjkp[0], cj1 = cjkp[1];
    // this instance: p==5, q==0 -> sr^p = sr^5 (3 muls), sr^q = 1 (uniform branch)
    const bool fastpq = (P0 == 5.f && P1 == 5.f && P2 == 5.f &&
                         Q0 == 0.f && Q1 == 0.f && Q2 == 0.f);

    // issue all global loads up front: two independent gather chains in flight
    const int    njA = nbr[tA];
    const int    njB = nbr[tB];
    const float4 pjA = pk[njA];
    const float4 pjB = pk[njB];
    const float4 piA = pk[tA >> 4];
    const float4 piB = pk[tB >> 4];

    float acc = 0.0f;

    DO_PAIR(piA, pjA)    // phase A
    DO_PAIR(piB, pjB)    // phase B (reuses comp[grp]; same-wave in-order DS ops)

    // wave reduce (64 lanes) -> block reduce -> contention-free partial store
    for (int o = 32; o > 0; o >>= 1) acc += __shfl_down(acc, o);
    if (lane == 0) wsum[tid >> 6] = acc;
    __syncthreads();
    if (tid == 0) {
        float s = 0.0f;
        for (int w = 0; w < BLOCK / 64; ++w) s += wsum[w];
        partial[blockIdx.x] = s;
    }
}

// Single-block final reduction over NBLK partials.
__global__ __launch_bounds__(1024) void sw_reduce(const float* __restrict__ partial,
                                                  float* __restrict__ out) {
    __shared__ float wsum[16];
    float s = 0.0f;
    for (int k = threadIdx.x; k < NBLK; k += 1024) s += partial[k];
    for (int o = 32; o > 0; o >>= 1) s += __shfl_down(s, o);
    if ((threadIdx.x & 63) == 0) wsum[threadIdx.x >> 6] = s;
    __syncthreads();
    if (threadIdx.x == 0) {
        float r = 0.0f;
        for (int w = 0; w < 16; ++w) r += wsum[w];
        out[0] = r;
    }
}

extern "C" void kernel_launch(void* const* d_in, const int* in_sizes, int n_in,
                              void* d_out, int out_size, void* d_ws, size_t ws_size,
                              hipStream_t stream) {
    const float* coords = (const float*)d_in[0];
    const float* A      = (const float*)d_in[1];
    const float* B      = (const float*)d_in[2];
    const float* p      = (const float*)d_in[3];
    const float* q      = (const float*)d_in[4];
    const float* sigma  = (const float*)d_in[5];
    const float* gamma  = (const float*)d_in[6];
    const float* cutoff = (const float*)d_in[7];
    const float* lam    = (const float*)d_in[8];
    const float* cb0    = (const float*)d_in[9];
    const float* cjk    = (const float*)d_in[10];
    const int*   elems  = (const int*)d_in[11];
    const int*   nbr    = (const int*)d_in[12];
    float* out = (float*)d_out;

    float4* pk      = (float4*)d_ws;                          // 1.6 MB
    float*  partial = (float*)((char*)d_ws + N_ATOMS * 16);   // 12.5 KB

    sw_pack<<<(N_ATOMS + 255) / 256, 256, 0, stream>>>(coords, elems, pk);
    sw_pairs<<<NBLK, BLOCK, 0, stream>>>(
        pk, nbr, A, B, p, q, sigma, gamma, cutoff, lam, cb0, cjk, partial);
    sw_reduce<<<1, 1024, 0, stream>>>(partial, out);
}